// Round 5
// baseline (1004.806 us; speedup 1.0000x reference)
//
#include <hip/hip_runtime.h>
#include <stdint.h>

// LSTM decoder: VOCAB=32000, EMBED=512, HIDDEN=1024, B=32, S=48.
// Plan:
//   1. cast3: W_ih, W_hh, hidden -> bf16 (fc_W cast is folded into step 4)
//   2. gather X[s][b][:] = emb[inputs[b][s]] as bf16 (+ zero barrier state)
//   3. GEMM1: Xg[1536,4096] = X @ W_ih^T + b_ih + b_hh   (fp32 out, 128-tile)
//   4. ONE persistent kernel runs all 48 LSTM steps.
//      - W_hh fragments resident in VGPRs (zero loads/step)
//      - xg prefetched during the previous barrier wait
//      - h exchange: writers sc0/sc1 write-through stores; readers do a
//        per-step agent-acquire fence (buffer_inv sc1) then NORMAL cached
//        loads -> each XCD pulls h once from L3, 32 WGs share via L2
//        (was 16 MB/step of L3 point-reads with sc0/sc1 loads)
//      - fast sigmoid/tanh via v_exp + v_rcp (libm tanhf is branchy)
//      - fc_W fp32->bf16 cast pipelined into the barrier-wait slack
//      - hierarchical barrier (8 group lines -> root -> release), poll on
//        a clean release line, no s_sleep; final step skips the barrier
//   5. GEMM2: 256x128-tile GEMM (8 waves); logits scattered to [B][S][V].

typedef unsigned short u16;
typedef __attribute__((ext_vector_type(8))) short bf16x8;
typedef __attribute__((ext_vector_type(4))) float floatx4;
struct alignas(8) us4 { u16 x, y, z, w; };

#define BATCH 32
#define SEQ   48
#define EMBED 512
#define HID   1024
#define VOCAB 32000
#define MROWS (SEQ * BATCH)   // 1536

#define FCW_F4    8192000     // VOCAB*HID/4 float4 chunks of fc_W
#define CAST_STEP 196608      // 256 WG * 256 thr * 3 f4 per step

__device__ __forceinline__ u16 f2bf(float f) {
  unsigned u = __float_as_uint(f);
  u += 0x7FFF + ((u >> 16) & 1);   // round-to-nearest-even
  return (u16)(u >> 16);
}

__device__ __forceinline__ floatx4 mfma16(bf16x8 a, bf16x8 b, floatx4 c) {
  return __builtin_amdgcn_mfma_f32_16x16x32_bf16(a, b, c, 0, 0, 0);
}

// async global->LDS, 16B per lane; lds base must be wave-uniform
typedef __attribute__((address_space(1))) unsigned int as1_uint;
typedef __attribute__((address_space(3))) unsigned int as3_uint;
__device__ __forceinline__ void gl_lds16(const void* g, void* l) {
  __builtin_amdgcn_global_load_lds((as1_uint*)g, (as3_uint*)l, 16, 0, 0);
}

// fast activations: v_exp_f32 + v_rcp_f32. Error ~1e-7 rel, far below the
// bf16 quantum that dominates absmax. Clamp keeps exp finite (no inf*0).
__device__ __forceinline__ float rcp_(float x) { return __builtin_amdgcn_rcpf(x); }
__device__ __forceinline__ float sig_(float x) { return rcp_(1.0f + __expf(-x)); }
__device__ __forceinline__ float tanh_(float x) {
  float xc = fminf(15.f, fmaxf(-15.f, x));
  float e = __expf(-2.0f * xc);
  return (1.0f - e) * rcp_(1.0f + e);
}

// plain cached 16B load; caller batches issues then drains once with
// s_waitcnt vmcnt(0) + sched_barrier(0) before any consumer (rule #18)
__device__ __forceinline__ void ld_n16(bf16x8& d, const u16* p) {
  asm volatile("global_load_dwordx4 %0, %1, off" : "=&v"(d) : "v"(p));
}

// barrier state layout (u32 indices within bar):
//   grp g   : bar[g*64]      g=0..7   (256B-spaced lines)
//   root    : bar[512]
//   release : bar[544]                (own line, polled)
#define BAR_U32S 576

// ---------------- cast fp32 -> bf16 for 3 tensors (fc_W handled in persist) ----
__global__ void cast3_kernel(const float* __restrict__ s0, u16* __restrict__ d0, int n0,
                             const float* __restrict__ s1, u16* __restrict__ d1, int n1,
                             const float* __restrict__ s2, u16* __restrict__ d2, int n2) {
  int i = blockIdx.x * blockDim.x + threadIdx.x;   // one float4 per thread
  const float* src; u16* dst; int off;
  if (i < n0)                { src = s0; dst = d0; off = i; }
  else if (i < n0 + n1)      { src = s1; dst = d1; off = i - n0; }
  else if (i < n0 + n1 + n2) { src = s2; dst = d2; off = i - n0 - n1; }
  else return;
  float4 v = *(const float4*)(src + (size_t)off * 4);
  us4 o;
  o.x = f2bf(v.x); o.y = f2bf(v.y); o.z = f2bf(v.z); o.w = f2bf(v.w);
  *(us4*)(dst + (size_t)off * 4) = o;
}

// ---------------- embedding gather: X[s*32+b][:] = bf16(emb[idx[b][s]]) --------
// block 0 also zeroes the persistent-LSTM barrier state (graph replays reuse ws)
__global__ void gather_kernel(const int* __restrict__ idx, const float* __restrict__ emb,
                              u16* __restrict__ X, unsigned* __restrict__ bar) {
  int bid = blockIdx.x;          // = s*32 + b
  if (bid == 0) {
    for (int j = threadIdx.x; j < BAR_U32S; j += 128) bar[j] = 0u;
  }
  int s = bid >> 5, b = bid & 31;
  int t = idx[b * SEQ + s];
  const float* src = emb + (size_t)t * EMBED;
  u16* dst = X + (size_t)bid * EMBED;
  int e = threadIdx.x * 4;       // 128 threads * 4 = 512
  float4 v = *(const float4*)(src + e);
  us4 o;
  o.x = f2bf(v.x); o.y = f2bf(v.y); o.z = f2bf(v.z); o.w = f2bf(v.w);
  *(us4*)(dst + e) = o;
}

// ---------------- tiled bf16 GEMM (128x128): C = A @ B^T + bias ----------------
// used for GEMM1 (row-major out). 4 waves, BK=64, XOR-swizzled LDS chunks.
__global__ __launch_bounds__(256) void gemm_bt_kernel(
    const u16* __restrict__ A, const u16* __restrict__ B,
    const float* __restrict__ bias0, const float* __restrict__ bias1,
    float* __restrict__ C, int M, int N, int K) {
  __shared__ u16 As[128 * 64];   // row r: 8 chunks of 8 bf16; chunk p holds global chunk p^(r&7)
  __shared__ u16 Bs[128 * 64];

  const int tid = threadIdx.x;
  const int wave = tid >> 6, lane = tid & 63;
  const int l3 = lane >> 3, l7 = lane & 7;
  const int q = lane >> 4, rf = lane & 15;
  const int tn = blockIdx.x, tm = blockIdx.y;
  const int gm0 = tm * 128, gn0 = tn * 128;
  const int wm = (wave & 1) * 64, wn = (wave >> 1) * 64;

  floatx4 acc[4][4];
#pragma unroll
  for (int i = 0; i < 4; ++i)
#pragma unroll
    for (int j = 0; j < 4; ++j) acc[i][j] = (floatx4){0.f, 0.f, 0.f, 0.f};

  for (int k0 = 0; k0 < K; k0 += 64) {
#pragma unroll
    for (int i = 0; i < 4; ++i) {
      int e = wave * 4 + i;
      int r = e * 8 + l3;
      int qd = l7 ^ (r & 7);
      gl_lds16(A + (size_t)(gm0 + r) * K + k0 + qd * 8, (void*)(As + e * 512));
      gl_lds16(B + (size_t)(gn0 + r) * K + k0 + qd * 8, (void*)(Bs + e * 512));
    }
    __syncthreads();

#pragma unroll
    for (int kk = 0; kk < 64; kk += 32) {
      int jc = (kk >> 3) + q;
      bf16x8 af[4], bf[4];
#pragma unroll
      for (int mi = 0; mi < 4; ++mi) {
        int r = wm + mi * 16 + rf;
        af[mi] = *(const bf16x8*)(As + r * 64 + (jc ^ (r & 7)) * 8);
      }
#pragma unroll
      for (int ni = 0; ni < 4; ++ni) {
        int r = wn + ni * 16 + rf;
        bf[ni] = *(const bf16x8*)(Bs + r * 64 + (jc ^ (r & 7)) * 8);
      }
#pragma unroll
      for (int mi = 0; mi < 4; ++mi)
#pragma unroll
        for (int ni = 0; ni < 4; ++ni)
          acc[mi][ni] = mfma16(af[mi], bf[ni], acc[mi][ni]);
    }
    __syncthreads();
  }

#pragma unroll
  for (int ni = 0; ni < 4; ++ni) {
    int n = gn0 + wn + ni * 16 + rf;
    float bv = bias0[n];
    if (bias1) bv += bias1[n];
#pragma unroll
    for (int mi = 0; mi < 4; ++mi) {
#pragma unroll
      for (int r = 0; r < 4; ++r) {
        int m = gm0 + wm + mi * 16 + q * 4 + r;
        C[(size_t)m * N + n] = acc[mi][ni][r] + bv;
      }
    }
  }
}

// ---------------- tiled bf16 GEMM (256x128, 8 waves): logits + scatter ---------
// 256-row m-tile halves the fc_W (B) L2 refetch: 6 m-tiles instead of 12.
// out: C[(b*SEQ + s)*N + n] with b=m&31, s=m>>5  (logits scatter)
__global__ __launch_bounds__(512) void gemm_bt256_kernel(
    const u16* __restrict__ A, const u16* __restrict__ B,
    const float* __restrict__ bias0, float* __restrict__ C,
    int N, int K) {
  __shared__ u16 As[256 * 64];   // 32 KB
  __shared__ u16 Bs[128 * 64];   // 16 KB

  const int tid = threadIdx.x;
  const int wave = tid >> 6, lane = tid & 63;   // 8 waves
  const int l3 = lane >> 3, l7 = lane & 7;
  const int q = lane >> 4, rf = lane & 15;
  const int tn = blockIdx.x, tm = blockIdx.y;
  const int gm0 = tm * 256, gn0 = tn * 128;
  const int wm = (wave & 3) * 64, wn = (wave >> 2) * 64;

  floatx4 acc[4][4];
#pragma unroll
  for (int i = 0; i < 4; ++i)
#pragma unroll
    for (int j = 0; j < 4; ++j) acc[i][j] = (floatx4){0.f, 0.f, 0.f, 0.f};

  for (int k0 = 0; k0 < K; k0 += 64) {
#pragma unroll
    for (int i = 0; i < 6; ++i) {
      int e = wave * 6 + i;
      if (e < 32) {
        int r = e * 8 + l3;
        int qd = l7 ^ (r & 7);
        gl_lds16(A + (size_t)(gm0 + r) * K + k0 + qd * 8, (void*)(As + e * 512));
      } else {
        int e2 = e - 32;
        int r = e2 * 8 + l3;
        int qd = l7 ^ (r & 7);
        gl_lds16(B + (size_t)(gn0 + r) * K + k0 + qd * 8, (void*)(Bs + e2 * 512));
      }
    }
    __syncthreads();

#pragma unroll
    for (int kk = 0; kk < 64; kk += 32) {
      int jc = (kk >> 3) + q;
      bf16x8 af[4], bf[4];
#pragma unroll
      for (int mi = 0; mi < 4; ++mi) {
        int r = wm + mi * 16 + rf;
        af[mi] = *(const bf16x8*)(As + r * 64 + (jc ^ (r & 7)) * 8);
      }
#pragma unroll
      for (int ni = 0; ni < 4; ++ni) {
        int r = wn + ni * 16 + rf;
        bf[ni] = *(const bf16x8*)(Bs + r * 64 + (jc ^ (r & 7)) * 8);
      }
#pragma unroll
      for (int mi = 0; mi < 4; ++mi)
#pragma unroll
        for (int ni = 0; ni < 4; ++ni)
          acc[mi][ni] = mfma16(af[mi], bf[ni], acc[mi][ni]);
    }
    __syncthreads();
  }

#pragma unroll
  for (int ni = 0; ni < 4; ++ni) {
    int n = gn0 + wn + ni * 16 + rf;
    float bv = bias0[n];
#pragma unroll
    for (int mi = 0; mi < 4; ++mi) {
#pragma unroll
      for (int r = 0; r < 4; ++r) {
        int m = gm0 + wm + mi * 16 + q * 4 + r;
        int b = m & 31, s = m >> 5;
        C[((size_t)b * SEQ + s) * N + n] = acc[mi][ni][r] + bv;
      }
    }
  }
}

// store a pending cast chunk (loads were issued >= 1 step earlier)
__device__ __forceinline__ void cast_store(const float4* cv, int pend,
                                           u16* __restrict__ dst) {
#pragma unroll
  for (int k = 0; k < 3; ++k) {
    int i = pend + k * 65536;
    if (i < FCW_F4) {
      us4 o;
      o.x = f2bf(cv[k].x); o.y = f2bf(cv[k].y);
      o.z = f2bf(cv[k].z); o.w = f2bf(cv[k].w);
      *(us4*)(dst + (size_t)i * 4) = o;
    }
  }
}

// ---------------- persistent LSTM: all 48 steps ----------------
// 256 WGs x 256 thr, 1 WG/CU. WG g owns 4 hidden units u0=4g.
// Post-release path per step: acquire-fence (buffer_inv sc1) -> 16 normal
// h loads (L2-shared within each XCD) -> drain -> 16 MFMA -> LDS reduce ->
// fast activations (c in fp32 regs) -> packed sc0/sc1 h store -> drain ->
// hierarchical arrive. fc_W cast chunks ride in the barrier-wait slack.
__global__ __launch_bounds__(256, 1) void lstm_persist5_kernel(
    const u16* __restrict__ Whh,      // [4096][1024] bf16
    const float* __restrict__ xg_all, // [48][32][4096] fp32
    const float* __restrict__ c_init, // [32][1024] fp32
    u16* __restrict__ Hall,           // [49][32][1024] bf16, slot 0 prefilled
    unsigned* __restrict__ bar,       // barrier state (pre-zeroed)
    const float* __restrict__ fcw_src,// [32000][1024] fp32
    u16* __restrict__ fcw_dst) {      // [32000][1024] bf16
  const int bid = blockIdx.x;
  const int u0 = bid * 4;
  const int tid = threadIdx.x;
  const int wave = tid >> 6, lane = tid & 63;
  const int q = lane >> 4, rf = lane & 15;
  const int gate = rf >> 2, du = rf & 3;
  const int brow = gate * HID + u0 + du;

  __shared__ float red[4][32][16];   // [wave][batch][n]

  const int ab = tid >> 2, ad = tid & 3;   // activation thread: (batch, unit)
  float c_reg = 0.f;
  if (tid < 128) c_reg = c_init[ab * HID + u0 + ad];

  // W_hh fragments resident in registers for the whole kernel (32 VGPRs)
  const u16* wp = Whh + (size_t)brow * HID + wave * 256 + q * 8;
  bf16x8 wv[8];
#pragma unroll
  for (int i = 0; i < 8; ++i) ld_n16(wv[i], wp + i * 32);
  // (drained by the first per-step vmcnt(0) below)

  // prefetch xg for step 0
  float xgv[4];
  if (tid < 128) {
#pragma unroll
    for (int gt = 0; gt < 4; ++gt) xgv[gt] = xg_all[ab * 4096 + gt * HID + u0 + ad];
  }

  // fc_W cast pipeline: issue loads for chunk 47 now; stored at step 0
  float4 cv[3];
  int pend = 47 * CAST_STEP + bid * 256 + tid;
#pragma unroll
  for (int k = 0; k < 3; ++k) {
    int i = pend + k * 65536;
    if (i < FCW_F4) cv[k] = *(const float4*)(fcw_src + (size_t)i * 4);
  }

  unsigned* gcnt    = bar + (bid & 7) * 64;
  unsigned* root    = bar + 512;
  unsigned* release = bar + 544;

  for (int s = 0; s < SEQ; ++s) {
    if (s > 0) {
      if (tid == 0) {
        while (__hip_atomic_load(release, __ATOMIC_RELAXED,
                                 __HIP_MEMORY_SCOPE_AGENT) < (unsigned)s) { }
      }
      __syncthreads();
      // invalidate L1 + stale L2 lines, then read h with NORMAL cached
      // loads: each XCD pulls the 64KB h once from L3; its 32 WGs hit L2.
      __builtin_amdgcn_fence(__ATOMIC_ACQUIRE, "agent");
    }

    const u16* a0p = Hall + (size_t)s * BATCH * HID + (size_t)rf * HID + wave * 256 + q * 8;
    const u16* a1p = a0p + 16 * HID;
    bf16x8 a0v[8], a1v[8];
#pragma unroll
    for (int i = 0; i < 8; ++i) {
      ld_n16(a0v[i], a0p + i * 32);
      ld_n16(a1v[i], a1p + i * 32);
    }
    asm volatile("s_waitcnt vmcnt(0)" ::: "memory");
    __builtin_amdgcn_sched_barrier(0);

    floatx4 acc0 = {0.f, 0.f, 0.f, 0.f}, acc1 = {0.f, 0.f, 0.f, 0.f};
#pragma unroll
    for (int i = 0; i < 8; ++i) {
      acc0 = mfma16(a0v[i], wv[i], acc0);
      acc1 = mfma16(a1v[i], wv[i], acc1);
    }

#pragma unroll
    for (int r = 0; r < 4; ++r) {
      red[wave][q * 4 + r][rf] = acc0[r];
      red[wave][16 + q * 4 + r][rf] = acc1[r];
    }
    __syncthreads();

    if (tid < 128) {
      float g4[4];
#pragma unroll
      for (int gt = 0; gt < 4; ++gt) {
        int n = gt * 4 + ad;
        float v = red[0][ab][n] + red[1][ab][n] + red[2][ab][n] + red[3][ab][n];
        g4[gt] = v + xgv[gt];
      }
      float i_ = sig_(g4[0]);
      float f_ = sig_(g4[1]);
      float gg = tanh_(g4[2]);
      float o_ = sig_(g4[3]);
      c_reg = f_ * c_reg + i_ * gg;
      float hv = o_ * tanh_(c_reg);
      u16 hb = f2bf(hv);
      float hn = __shfl_xor(hv, 1);      // partner unit (ad^1), same wave
      u16 nb = f2bf(hn);
      if ((tid & 1) == 0) {              // ad even: pack (ad, ad+1) -> u32
        unsigned w = (unsigned)hb | ((unsigned)nb << 16);
        unsigned* dst = (unsigned*)(Hall + (size_t)(s + 1) * BATCH * HID +
                                    ab * HID + u0 + ad);
        __hip_atomic_store(dst, w, __ATOMIC_RELAXED, __HIP_MEMORY_SCOPE_AGENT);
      }
    }
    // __syncthreads drains each wave's vmcnt -> h stores are at the
    // coherence point before this WG's arrival is visible.
    __syncthreads();

    if (s < SEQ - 1) {
      if (tid == 0) {
        unsigned old = __hip_atomic_fetch_add(gcnt, 1u, __ATOMIC_RELAXED,
                                              __HIP_MEMORY_SCOPE_AGENT);
        if (old + 1 == 32u * (unsigned)(s + 1)) {      // last in group
          unsigned r = __hip_atomic_fetch_add(root, 1u, __ATOMIC_RELAXED,
                                              __HIP_MEMORY_SCOPE_AGENT);
          if (r + 1 == 8u * (unsigned)(s + 1)) {       // last overall
            __hip_atomic_store(release, (unsigned)(s + 1), __ATOMIC_RELAXED,
                               __HIP_MEMORY_SCOPE_AGENT);
          }
        }
      }
      // fc_W cast: store the chunk loaded last step, issue loads for this
      // step's chunk. Both overlap the barrier wait; the next fence's
      // vmcnt(0) lands long after these loads were issued.
      cast_store(cv, pend, fcw_dst);
      pend = s * CAST_STEP + bid * 256 + tid;
#pragma unroll
      for (int k = 0; k < 3; ++k) {
        int i = pend + k * 65536;
        if (i < FCW_F4) cv[k] = *(const float4*)(fcw_src + (size_t)i * 4);
      }
      // prefetch xg for s+1 — overlaps the barrier wait at the next loop top
      if (tid < 128) {
        const float* xgn = xg_all + (size_t)(s + 1) * BATCH * 4096;
#pragma unroll
        for (int gt = 0; gt < 4; ++gt) xgv[gt] = xgn[ab * 4096 + gt * HID + u0 + ad];
      }
    }
  }
  // store the chunk loaded at s=46 (chunk 46)
  cast_store(cv, pend, fcw_dst);
}

extern "C" void kernel_launch(void* const* d_in, const int* in_sizes, int n_in,
                              void* d_out, int out_size, void* d_ws, size_t ws_size,
                              hipStream_t stream) {
  const int*   inputs = (const int*)d_in[0];
  const float* hidden = (const float*)d_in[1];
  const float* cell   = (const float*)d_in[2];
  const float* emb    = (const float*)d_in[3];
  const float* W_ih   = (const float*)d_in[4];
  const float* W_hh   = (const float*)d_in[5];
  const float* b_ih   = (const float*)d_in[6];
  const float* b_hh   = (const float*)d_in[7];
  const float* fc_W   = (const float*)d_in[8];
  const float* fc_b   = (const float*)d_in[9];
  float* out = (float*)d_out;

  char* ws = (char*)d_ws;
  // workspace layout (all 256B aligned), total ~108 MiB
  u16*   Xbf  = (u16*)(ws);                                  // 1536*512   bf16 = 1,572,864 B
  u16*   Wihb = (u16*)(ws + 1572864);                        // 4096*512   bf16 = 4,194,304 B
  u16*   Whhb = (u16*)(ws + 1572864 + 4194304);              // 4096*1024  bf16 = 8,388,608 B
  u16*   fcWb = (u16*)(ws + 14155776);                       // 32000*1024 bf16 = 65,536,000 B
  float* Xg   = (float*)(ws + 14155776 + 65536000);          // 1536*4096  f32  = 25,165,824 B
  u16*   Hall = (u16*)(ws + 104857600);                      // 49*32*1024 bf16 = 3,211,264 B
  unsigned* bar = (unsigned*)(ws + 104857600 + 3211264);     // barrier state

  // 1) casts to bf16 (W_ih, W_hh, hidden -> Hall[0]); fc_W is cast inside
  //    the persistent kernel's barrier-wait slack
  const int n0 = 4096 * 512 / 4, n1 = 4096 * 1024 / 4, n2 = BATCH * HID / 4;
  const int ncast = n0 + n1 + n2;
  cast3_kernel<<<(ncast + 255) / 256, 256, 0, stream>>>(
      W_ih, Wihb, n0, W_hh, Whhb, n1, hidden, Hall, n2);

  // 2) embedding gather (time-major) + barrier-state zero
  gather_kernel<<<MROWS, 128, 0, stream>>>(inputs, emb, Xbf, bar);

  // 3) GEMM1: Xg = X @ W_ih^T + b_ih + b_hh
  gemm_bt_kernel<<<dim3(4096 / 128, MROWS / 128), 256, 0, stream>>>(
      Xbf, Wihb, b_ih, b_hh, Xg, MROWS, 4096, EMBED);

  // 4) all 48 recurrent steps in ONE persistent kernel (+ fc_W cast)
  lstm_persist5_kernel<<<256, 256, 0, stream>>>(Whhb, Xg, cell, Hall, bar,
                                                fc_W, fcWb);

  // 5) GEMM2 (256x128 tiles): logits = H_all[1..48] @ fc_W^T + fc_b, scattered
  gemm_bt256_kernel<<<dim3(VOCAB / 128, MROWS / 256), 512, 0, stream>>>(
      Hall + (size_t)BATCH * HID, fcWb, fc_b, out, VOCAB, HID);
}